// Round 3
// baseline (204.694 us; speedup 1.0000x reference)
//
#include <hip/hip_runtime.h>
#include <hip/hip_cooperative_groups.h>
#include <math.h>

namespace cg = cooperative_groups;

#define K_MAX 256
#define NB 384   // cooperative grid blocks (<=2 per CU, co-resident)
#define NT 256

struct Ws {
    unsigned long long part_packed[NB * K_MAX]; // (q_bits<<32)|~idx per-block maxes
    unsigned int       part_beta[NB * K_MAX];   // beta-as-uint per-block maxes
    float              part_bg[NB];
    float              part_nb[NB];
    float4             cvec[K_MAX];             // (2ax, 2ay, 2az, -|a|^2)
    float              qv[K_MAX];               // q_ak
    float              bak[K_MAX];              // 1 - beta_ak
    float              bg_total;
    float              nb_total;
    float              Lv;
};

__global__ void __launch_bounds__(NT) k_fused(const float* __restrict__ x,
        const float* __restrict__ beta, const int* __restrict__ y,
        const int* __restrict__ Kp, const float* __restrict__ Sbp,
        const float* __restrict__ qminp, Ws* __restrict__ w,
        float* __restrict__ out, int N) {
    __shared__ unsigned long long s_u64[NT];
    __shared__ unsigned int s_u32[NT];
    __shared__ float s_red[NT];
    __shared__ float4 s_c[K_MAX];
    __shared__ float s_q[K_MAX];

    cg::grid_group grid = cg::this_grid();
    int t = threadIdx.x;
    int b = blockIdx.x;
    int K = Kp[0];
    float qmin = qminp[0];

    if (b == 0 && t == 0) atomicExch(&w->Lv, 0.f);  // device-scope init (ws is poisoned)

    // ---- phase 1: privatized per-block segment maxima + background sums ----
    s_u64[t] = 0ULL;
    s_u32[t] = 0u;
    __syncthreads();
    float bg = 0.f, nbc = 0.f;
    for (int i = b * NT + t; i < N; i += NB * NT) {
        float be = beta[i];
        int yi = y[i];
        if (yi < 0) { bg += be; nbc += 1.f; }
        else {
            atomicMax(&s_u32[yi], __float_as_uint(be));
            float a = atanhf(be);
            float q = fmaf(a, a, qmin);
            unsigned long long p = ((unsigned long long)__float_as_uint(q) << 32)
                                 | (unsigned long long)(~(unsigned int)i);
            atomicMax(&s_u64[yi], p);
        }
    }
    __syncthreads();
    w->part_packed[b * K_MAX + t] = s_u64[t];
    w->part_beta[b * K_MAX + t]  = s_u32[t];
    s_red[t] = bg;
    __syncthreads();
    for (int s = NT / 2; s > 0; s >>= 1) { if (t < s) s_red[t] += s_red[t + s]; __syncthreads(); }
    if (t == 0) w->part_bg[b] = s_red[0];
    __syncthreads();
    s_red[t] = nbc;
    __syncthreads();
    for (int s = NT / 2; s > 0; s >>= 1) { if (t < s) s_red[t] += s_red[t + s]; __syncthreads(); }
    if (t == 0) w->part_nb[b] = s_red[0];

    grid.sync();

    // ---- phase 2: block k folds cluster k; blocks K, K+1 fold bg/nb ----
    if (b < K) {
        unsigned long long m = 0ULL; unsigned int bb = 0u;
        for (int p = t; p < NB; p += NT) {
            unsigned long long v = w->part_packed[p * K_MAX + b];
            m = (v > m) ? v : m;
            unsigned int u = w->part_beta[p * K_MAX + b];
            bb = (u > bb) ? u : bb;
        }
        s_u64[t] = m; s_u32[t] = bb;
        __syncthreads();
        for (int s = NT / 2; s > 0; s >>= 1) {
            if (t < s) {
                unsigned long long v = s_u64[t + s]; if (v > s_u64[t]) s_u64[t] = v;
                unsigned int u = s_u32[t + s]; if (u > s_u32[t]) s_u32[t] = u;
            }
            __syncthreads();
        }
        if (t == 0) {
            unsigned long long mm = s_u64[0];
            float q; unsigned int idx;
            if (mm == 0ULL) { q = 0.f; idx = 0u; }
            else { q = __uint_as_float((unsigned int)(mm >> 32)); idx = ~(unsigned int)mm; }
            float ax = x[idx * 3], ay = x[idx * 3 + 1], az = x[idx * 3 + 2];
            w->cvec[b] = make_float4(2.f * ax, 2.f * ay, 2.f * az,
                                     -(ax * ax + ay * ay + az * az));
            w->qv[b]  = q;
            w->bak[b] = 1.f - __uint_as_float(s_u32[0]);
        }
    } else if (b == K || b == K + 1) {
        const float* src = (b == K) ? w->part_bg : w->part_nb;
        float sum = 0.f;
        for (int p = t; p < NB; p += NT) sum += src[p];
        s_red[t] = sum;
        __syncthreads();
        for (int s = NT / 2; s > 0; s >>= 1) { if (t < s) s_red[t] += s_red[t + s]; __syncthreads(); }
        if (t == 0) { if (b == K) w->bg_total = s_red[0]; else w->nb_total = s_red[0]; }
    }

    grid.sync();

    // ---- phase 3: N x K potential; u = (1-|x|^2) + (-|a|^2) + 2 x.a = 1-|x-a|^2 ----
    if (t < K) { s_c[t] = w->cvec[t]; s_q[t] = w->qv[t]; }
    __syncthreads();
    float bsum = 0.f;
    for (int i = b * NT + t; i < N; i += NB * NT) {
        float x0 = x[i * 3], x1 = x[i * 3 + 1], x2 = x[i * 3 + 2];
        float be = beta[i];
        int yi = y[i];
        float a = atanhf(be);
        float qi = fmaf(a, a, qmin);
        float g = 1.f - (x0 * x0 + x1 * x1 + x2 * x2);
        float acc = 0.f;
        #pragma unroll 8
        for (int k = 0; k < K; ++k) {
            float4 c = s_c[k];   // wave-uniform LDS broadcast
            float u = fmaf(x0, c.x, fmaf(x1, c.y, fmaf(x2, c.z, g + c.w)));
            acc = fmaf(fmaxf(u, 0.f), s_q[k], acc);
        }
        if (yi >= 0) {   // swap repulsive for attractive on the member cluster
            float4 c = s_c[yi];
            float u = fmaf(x0, c.x, fmaf(x1, c.y, fmaf(x2, c.z, g + c.w)));
            acc += ((1.f - u) - fmaxf(u, 0.f)) * s_q[yi];
        }
        bsum += acc * qi;
    }
    s_red[t] = bsum;
    __syncthreads();
    for (int s = NT / 2; s > 0; s >>= 1) { if (t < s) s_red[t] += s_red[t + s]; __syncthreads(); }
    if (t == 0) atomicAdd(&w->Lv, s_red[0]);

    grid.sync();

    // ---- final: L_beta + L_v / N ----
    if (b == 0) {
        s_red[t] = (t < K) ? w->bak[t] : 0.f;
        __syncthreads();
        for (int s = NT / 2; s > 0; s >>= 1) { if (t < s) s_red[t] += s_red[t + s]; __syncthreads(); }
        if (t == 0) {
            float Lv = atomicAdd(&w->Lv, 0.f);   // coherence-point read
            out[0] = s_red[0] / (float)K + Sbp[0] / w->nb_total * w->bg_total
                   + Lv / (float)N;
        }
    }
}

extern "C" void kernel_launch(void* const* d_in, const int* in_sizes, int n_in,
                              void* d_out, int out_size, void* d_ws, size_t ws_size,
                              hipStream_t stream) {
    const float* x     = (const float*)d_in[0];
    const float* beta  = (const float*)d_in[1];
    const int*   y     = (const int*)d_in[2];
    const int*   Kp    = (const int*)d_in[3];
    const float* Sbp   = (const float*)d_in[4];
    const float* qminp = (const float*)d_in[5];
    float* out = (float*)d_out;
    int N = in_sizes[1];
    Ws* w = (Ws*)d_ws;

    void* args[] = { (void*)&x, (void*)&beta, (void*)&y, (void*)&Kp, (void*)&Sbp,
                     (void*)&qminp, (void*)&w, (void*)&out, (void*)&N };
    hipLaunchCooperativeKernel((void*)k_fused, dim3(NB), dim3(NT), args, 0, stream);
}

// Round 4
// 82.939 us; speedup vs baseline: 2.4680x; 2.4680x over previous
//
#include <hip/hip_runtime.h>
#include <math.h>

#define K_MAX 256
#define P1 64      // stage-1 partial blocks
#define NT 256

struct Ws {
    unsigned long long part_packed[P1 * K_MAX]; // (q_bits<<32)|~idx per-block maxes
    unsigned int       part_beta[P1 * K_MAX];   // beta-as-uint per-block maxes
    float              part_bg[P1];
    float              part_nb[P1];
    float4             cvec[K_MAX];             // (2q*ax, 2q*ay, 2q*az, q*(1-|a|^2))
    float              qv[K_MAX];               // q_ak
    float              bak[K_MAX];              // 1 - beta_ak
    float              bg_total;
    float              nb_total;
};

__device__ __forceinline__ float wave_sum(float v) {
    #pragma unroll
    for (int o = 32; o > 0; o >>= 1) v += __shfl_down(v, o, 64);
    return v;
}

// Stage 1: privatized per-block segment maxima in LDS, plain coalesced stores out.
__global__ void __launch_bounds__(NT) k_scan(const float* __restrict__ beta,
        const int* __restrict__ y, const float* __restrict__ qminp,
        Ws* __restrict__ w, int N) {
    __shared__ unsigned long long s_u64[K_MAX];
    __shared__ unsigned int s_u32[K_MAX];
    __shared__ float s_w[8];
    int t = threadIdx.x;
    int b = blockIdx.x;
    s_u64[t] = 0ULL;
    s_u32[t] = 0u;
    __syncthreads();
    float qmin = qminp[0];
    float bg = 0.f, nbc = 0.f;
    for (int i = b * NT + t; i < N; i += P1 * NT) {
        float be = beta[i];
        int yi = y[i];
        if (yi < 0) { bg += be; nbc += 1.f; }
        else {
            atomicMax(&s_u32[yi], __float_as_uint(be));
            float a = atanhf(be);
            float q = fmaf(a, a, qmin);
            unsigned long long p = ((unsigned long long)__float_as_uint(q) << 32)
                                 | (unsigned long long)(~(unsigned int)i);
            atomicMax(&s_u64[yi], p);
        }
    }
    __syncthreads();
    w->part_packed[b * K_MAX + t] = s_u64[t];
    w->part_beta[b * K_MAX + t]  = s_u32[t];
    int lane = t & 63, wid = t >> 6;
    float r1 = wave_sum(bg);
    float r2 = wave_sum(nbc);
    if (lane == 0) { s_w[wid] = r1; s_w[4 + wid] = r2; }
    __syncthreads();
    if (t == 0) w->part_bg[b] = s_w[0] + s_w[1] + s_w[2] + s_w[3];
    if (t == 1) w->part_nb[b] = s_w[4] + s_w[5] + s_w[6] + s_w[7];
}

// Stage 2: block k (single wave of 64) folds cluster k's 64 partials;
// blocks 256/257 fold bg/nb; block 256 also zero-inits out[0].
__global__ void __launch_bounds__(64) k_reduce(const float* __restrict__ x,
        Ws* __restrict__ w, float* __restrict__ out) {
    int b = blockIdx.x, t = threadIdx.x;
    if (b < K_MAX) {
        unsigned long long m = w->part_packed[t * K_MAX + b];
        unsigned int bb = w->part_beta[t * K_MAX + b];
        #pragma unroll
        for (int o = 32; o > 0; o >>= 1) {
            unsigned long long v = __shfl_down(m, o, 64);  if (v > m)  m = v;
            unsigned int       u = __shfl_down(bb, o, 64); if (u > bb) bb = u;
        }
        if (t == 0) {
            float q; unsigned int idx;
            if (m == 0ULL) { q = 0.f; idx = 0u; }
            else { q = __uint_as_float((unsigned int)(m >> 32)); idx = ~(unsigned int)m; }
            float ax = x[idx * 3], ay = x[idx * 3 + 1], az = x[idx * 3 + 2];
            w->cvec[b] = make_float4(2.f * q * ax, 2.f * q * ay, 2.f * q * az,
                                     q * (1.f - (ax * ax + ay * ay + az * az)));
            w->qv[b]  = q;
            w->bak[b] = 1.f - __uint_as_float(bb);
        }
    } else {
        const float* src = (b == K_MAX) ? w->part_bg : w->part_nb;
        float s = wave_sum(src[t]);
        if (t == 0) {
            if (b == K_MAX) { w->bg_total = s; out[0] = 0.f; }
            else            { w->nb_total = s; }
        }
    }
}

// Stage 3: N x K potential. uq = q*(1-|x-a|^2) via premultiplied coeffs:
// uq = c.x*x0 + c.y*x1 + c.z*x2 + q*(-h) + c.w   (4 fma + max + add per k).
// Block 0 also folds L_beta into out.
__global__ void __launch_bounds__(NT) k_main(const float* __restrict__ x,
        const float* __restrict__ beta, const int* __restrict__ y,
        const int* __restrict__ Kp, const float* __restrict__ Sbp,
        const float* __restrict__ qminp, const Ws* __restrict__ w,
        float* __restrict__ out, int N) {
    __shared__ float4 s_c[K_MAX];
    __shared__ float s_q[K_MAX];
    __shared__ float s_w[8];
    int t = threadIdx.x;
    s_c[t] = w->cvec[t];
    s_q[t] = w->qv[t];
    __syncthreads();
    int i = blockIdx.x * NT + t;
    float contrib = 0.f;
    if (i < N) {
        float x0 = x[i * 3], x1 = x[i * 3 + 1], x2 = x[i * 3 + 2];
        float be = beta[i];
        int yi = y[i];
        float a = atanhf(be);
        float qi = fmaf(a, a, qminp[0]);
        float negh = -(x0 * x0 + x1 * x1 + x2 * x2);
        float acc = 0.f;
        #pragma unroll 8
        for (int k = 0; k < K_MAX; ++k) {     // empty/out-of-range clusters have q=0 -> uq=0
            float4 c = s_c[k];
            float t0 = fmaf(s_q[k], negh, c.w);
            float uq = fmaf(c.x, x0, fmaf(c.y, x1, fmaf(c.z, x2, t0)));
            acc += fmaxf(uq, 0.f);
        }
        if (yi >= 0) {   // member: attractive q*d replaces repulsive; q*d = q - uq
            float4 c = s_c[yi];
            float qk = s_q[yi];
            float t0 = fmaf(qk, negh, c.w);
            float uq = fmaf(c.x, x0, fmaf(c.y, x1, fmaf(c.z, x2, t0)));
            acc += (qk - uq) - fmaxf(uq, 0.f);
        }
        contrib = acc * qi;
    }
    int lane = t & 63, wid = t >> 6;
    float r = wave_sum(contrib);
    if (lane == 0) s_w[wid] = r;
    __syncthreads();
    if (t == 0) atomicAdd(out, (s_w[0] + s_w[1] + s_w[2] + s_w[3]) * (1.f / (float)N));
    if (blockIdx.x == 0) {
        int K = Kp[0];
        float v = wave_sum((t < K) ? w->bak[t] : 0.f);
        if (lane == 0) s_w[4 + wid] = v;
        __syncthreads();
        if (t == 0) {
            float sb = s_w[4] + s_w[5] + s_w[6] + s_w[7];
            atomicAdd(out, sb / (float)K + Sbp[0] / w->nb_total * w->bg_total);
        }
    }
}

extern "C" void kernel_launch(void* const* d_in, const int* in_sizes, int n_in,
                              void* d_out, int out_size, void* d_ws, size_t ws_size,
                              hipStream_t stream) {
    const float* x     = (const float*)d_in[0];
    const float* beta  = (const float*)d_in[1];
    const int*   y     = (const int*)d_in[2];
    const int*   Kp    = (const int*)d_in[3];
    const float* Sbp   = (const float*)d_in[4];
    const float* qminp = (const float*)d_in[5];
    float* out = (float*)d_out;
    int N = in_sizes[1];
    Ws* w = (Ws*)d_ws;
    int nb = (N + NT - 1) / NT;

    k_scan<<<P1, NT, 0, stream>>>(beta, y, qminp, w, N);
    k_reduce<<<K_MAX + 2, 64, 0, stream>>>(x, w, out);
    k_main<<<nb, NT, 0, stream>>>(x, beta, y, Kp, Sbp, qminp, w, out, N);
}